// Round 1
// baseline (536.355 us; speedup 1.0000x reference)
//
#include <hip/hip_runtime.h>
#include <stdint.h>

#define M_PIX 8192
#define N_CB  16384
#define KD    256

typedef float  f32x4  __attribute__((ext_vector_type(4)));
typedef __bf16 bf16x8 __attribute__((ext_vector_type(8)));

// workspace layout (bytes)
#define OFF_CH   (0ULL)            // codebook hi  : 16384*256*2 = 8 MB
#define OFF_CL   (8ULL  << 20)     // codebook lo  : 8 MB
#define OFF_XH   (16ULL << 20)     // x hi         : 4 MB
#define OFF_XL   (20ULL << 20)     // x lo         : 4 MB
#define OFF_CBSQ (24ULL << 20)     // ||c||^2 fp32 : 64 KB
#define OFF_SLOT (25ULL << 20)     // top2 slots   : 8192*128*16 = 16 MB
#define WS_REQ   ((25ULL << 20) + (16ULL << 20))

__device__ __forceinline__ unsigned short f2bf(float v) {
  unsigned int u = __float_as_uint(v);
  u += 0x7FFFu + ((u >> 16) & 1u);   // round-to-nearest-even to bf16
  return (unsigned short)(u >> 16);
}
__device__ __forceinline__ float bf2f(unsigned short h) {
  return __uint_as_float(((unsigned int)h) << 16);
}
// order-preserving map fp32 -> u32 (handles negatives)
__device__ __forceinline__ unsigned int fkey(float s) {
  unsigned int f = __float_as_uint(s);
  return f ^ ((unsigned int)(((int)f) >> 31) | 0x80000000u);
}

// ---------------- kernel 1: convert to bf16 hi/lo + codebook norms ----------
__global__ __launch_bounds__(256) void prep_kernel(
    const float* __restrict__ x, const float* __restrict__ cb,
    unsigned short* __restrict__ Ch, unsigned short* __restrict__ Cl,
    unsigned short* __restrict__ Xh, unsigned short* __restrict__ Xl,
    float* __restrict__ cbsq) {
  const int wid = threadIdx.x >> 6, lane = threadIdx.x & 63;
  const int row = blockIdx.x * 4 + wid;        // grid = (N_CB+M_PIX)/4
  const bool isCb = (row < N_CB);
  const int rowL = isCb ? row : row - N_CB;
  const float* src = (isCb ? cb : x) + (size_t)rowL * KD;
  const float4 v = ((const float4*)src)[lane]; // 64 lanes * 4 = 256 elems

  unsigned short h0 = f2bf(v.x), h1 = f2bf(v.y), h2 = f2bf(v.z), h3 = f2bf(v.w);
  unsigned short l0 = f2bf(v.x - bf2f(h0)), l1 = f2bf(v.y - bf2f(h1)),
                 l2 = f2bf(v.z - bf2f(h2)), l3 = f2bf(v.w - bf2f(h3));
  uint2 ph = make_uint2((unsigned)h0 | ((unsigned)h1 << 16),
                        (unsigned)h2 | ((unsigned)h3 << 16));
  uint2 pl = make_uint2((unsigned)l0 | ((unsigned)l1 << 16),
                        (unsigned)l2 | ((unsigned)l3 << 16));
  const size_t o = (size_t)rowL * KD + (size_t)lane * 4;
  *(uint2*)(void*)((isCb ? Ch : Xh) + o) = ph;
  *(uint2*)(void*)((isCb ? Cl : Xl) + o) = pl;

  if (isCb) {
    float ss = v.x*v.x + v.y*v.y + v.z*v.z + v.w*v.w;  // fp32 norm (matches ref scale)
    #pragma unroll
    for (int off = 32; off > 0; off >>= 1) ss += __shfl_xor(ss, off);
    if (lane == 0) cbsq[row] = ss;
  }
}

// ---------------- kernel 2: fused split-bf16 GEMM + per-tile top-2 ----------
// s[p,n] = cbsq[n] - 2*(xh.ch + xh.cl + xl.ch)   (xl.cl dropped, ~4e-4 error)
// grid = (128 ntiles, 64 mtiles), 256 threads = 4 waves (2x2), wave tile 64x64
__global__ __launch_bounds__(256, 2) void gemm_top2_kernel(
    const unsigned short* __restrict__ Xh, const unsigned short* __restrict__ Xl,
    const unsigned short* __restrict__ Ch, const unsigned short* __restrict__ Cl,
    const float* __restrict__ cbsq, ulonglong2* __restrict__ slots) {
  __shared__ ulonglong2 lds_pair[128][33];   // +1 pad: break 512B-stride conflicts
  __shared__ ulonglong2 lds_half[128][2];

  const int tid = threadIdx.x;
  const int wid = tid >> 6, lane = tid & 63;
  const int wy = wid >> 1, wx = wid & 1;
  const int q = lane >> 4, c = lane & 15;
  const int m0 = blockIdx.y * 128, n0 = blockIdx.x * 128;
  const int arow = m0 + wy * 64 + c;   // A frag: m = lane&15 (+mi*16)
  const int brow = n0 + wx * 64 + c;   // B frag: n = lane&15 (+ni*16)

  const f32x4 zf = {0.f, 0.f, 0.f, 0.f};
  f32x4 acc[4][4];
  #pragma unroll
  for (int i = 0; i < 4; i++)
    #pragma unroll
    for (int j = 0; j < 4; j++) acc[i][j] = zf;

  #pragma unroll
  for (int ks = 0; ks < 8; ks++) {           // K = 8 * 32
    const int koff = ks * 32 + q * 8;        // k = quad*8 + j within MFMA
    bf16x8 ah[4], al[4], bh[4], bl[4];
    #pragma unroll
    for (int i = 0; i < 4; i++) {
      const size_t ao = (size_t)(arow + i * 16) * KD + koff;
      const size_t bo = (size_t)(brow + i * 16) * KD + koff;
      ah[i] = *(const bf16x8*)(const void*)(Xh + ao);
      al[i] = *(const bf16x8*)(const void*)(Xl + ao);
      bh[i] = *(const bf16x8*)(const void*)(Ch + bo);
      bl[i] = *(const bf16x8*)(const void*)(Cl + bo);
    }
    #pragma unroll
    for (int mi = 0; mi < 4; mi++)
      #pragma unroll
      for (int ni = 0; ni < 4; ni++) {
        acc[mi][ni] = __builtin_amdgcn_mfma_f32_16x16x32_bf16(ah[mi], bh[ni], acc[mi][ni], 0, 0, 0);
        acc[mi][ni] = __builtin_amdgcn_mfma_f32_16x16x32_bf16(ah[mi], bl[ni], acc[mi][ni], 0, 0, 0);
        acc[mi][ni] = __builtin_amdgcn_mfma_f32_16x16x32_bf16(al[mi], bh[ni], acc[mi][ni], 0, 0, 0);
      }
  }

  // epilogue: C/D layout col=lane&15, row=quad*4+reg (verified m89/m91)
  float cs[4];
  #pragma unroll
  for (int ni = 0; ni < 4; ni++) cs[ni] = cbsq[n0 + wx * 64 + ni * 16 + c];

  #pragma unroll
  for (int mi = 0; mi < 4; mi++) {
    #pragma unroll
    for (int r = 0; r < 4; r++) {
      unsigned long long b1 = ~0ULL, b2 = ~0ULL;
      #pragma unroll
      for (int ni = 0; ni < 4; ni++) {
        const int n = n0 + wx * 64 + ni * 16 + c;
        const float s = fmaf(-2.f, acc[mi][ni][r], cs[ni]);
        const unsigned long long key =
            ((unsigned long long)fkey(s) << 32) | (unsigned int)n;
        unsigned long long lo = key < b1 ? key : b1;
        unsigned long long hi = key < b1 ? b1 : key;
        b1 = lo; b2 = hi < b2 ? hi : b2;
      }
      lds_pair[wy * 64 + mi * 16 + q * 4 + r][wx * 16 + c] = make_ulonglong2(b1, b2);
    }
  }
  __syncthreads();

  {  // 2 threads per row, each merges 16 sorted pairs
    const int row = tid >> 1, half = tid & 1;
    unsigned long long B1 = ~0ULL, B2 = ~0ULL;
    #pragma unroll
    for (int g = 0; g < 16; g++) {
      const ulonglong2 p = lds_pair[row][half * 16 + g];
      unsigned long long m1 = p.x < B1 ? p.x : B1;
      unsigned long long t  = p.x < B1 ? B1 : p.x;
      unsigned long long mo = p.y < B2 ? p.y : B2;
      B1 = m1; B2 = t < mo ? t : mo;
    }
    lds_half[row][half] = make_ulonglong2(B1, B2);
  }
  __syncthreads();

  if (tid < 128) {
    const ulonglong2 a = lds_half[tid][0], b = lds_half[tid][1];
    unsigned long long m1 = a.x < b.x ? a.x : b.x;
    unsigned long long t  = a.x < b.x ? b.x : a.x;
    unsigned long long mo = a.y < b.y ? a.y : b.y;
    unsigned long long m2 = t < mo ? t : mo;
    slots[(size_t)(m0 + tid) * 128 + blockIdx.x] = make_ulonglong2(m1, m2);
  }
}

// ---------------- kernel 3: global top-2, exact fp32 rescore, gather --------
__global__ __launch_bounds__(256) void reduce_gather_kernel(
    const float* __restrict__ x, const float* __restrict__ cb,
    const float* __restrict__ cbsq, const ulonglong2* __restrict__ slots,
    float* __restrict__ out) {
  const int wid = threadIdx.x >> 6, lane = threadIdx.x & 63;
  const int pixel = blockIdx.x * 4 + wid;     // grid = 8192/4
  const ulonglong2* sp = slots + (size_t)pixel * 128;
  const ulonglong2 s0 = sp[lane];
  const ulonglong2 s1 = sp[64 + lane];

  unsigned long long b1 = s0.x, b2 = s0.y;
  { unsigned long long m1 = b1 < s1.x ? b1 : s1.x;
    unsigned long long t  = b1 < s1.x ? s1.x : b1;
    unsigned long long mo = b2 < s1.y ? b2 : s1.y;
    b1 = m1; b2 = t < mo ? t : mo; }
  #pragma unroll
  for (int off = 1; off < 64; off <<= 1) {
    unsigned long long o1 = __shfl_xor(b1, off), o2 = __shfl_xor(b2, off);
    unsigned long long m1 = b1 < o1 ? b1 : o1;
    unsigned long long t  = b1 < o1 ? o1 : b1;
    unsigned long long mo = b2 < o2 ? b2 : o2;
    b1 = m1; b2 = t < mo ? t : mo;
  }
  const int i1 = (int)(unsigned int)(b1 & 0xFFFFFFFFULL);
  const int i2 = (int)(unsigned int)(b2 & 0xFFFFFFFFULL);

  const float4 xv = ((const float4*)x)[(size_t)pixel * 64 + lane];
  const float4 c1 = ((const float4*)cb)[(size_t)i1 * 64 + lane];
  const float4 c2 = ((const float4*)cb)[(size_t)i2 * 64 + lane];
  float d1 = xv.x*c1.x + xv.y*c1.y + xv.z*c1.z + xv.w*c1.w;
  float d2 = xv.x*c2.x + xv.y*c2.y + xv.z*c2.z + xv.w*c2.w;
  #pragma unroll
  for (int off = 1; off < 64; off <<= 1) {
    d1 += __shfl_xor(d1, off);
    d2 += __shfl_xor(d2, off);
  }
  const float s1v = fmaf(-2.f, d1, cbsq[i1]);
  const float s2v = fmaf(-2.f, d2, cbsq[i2]);
  const int w = (s1v < s2v) ? i1 : (s2v < s1v) ? i2 : (i1 < i2 ? i1 : i2);
  ((float4*)out)[(size_t)pixel * 64 + lane] = ((const float4*)cb)[(size_t)w * 64 + lane];
}

// ---------------- fallback (only if ws too small): exact fp32 scan ----------
__global__ __launch_bounds__(256) void fallback_kernel(
    const float* __restrict__ x, const float* __restrict__ cb,
    float* __restrict__ out) {
  __shared__ float xs[256];
  __shared__ unsigned long long keys[4];
  __shared__ int widx;
  const int p = blockIdx.x;
  const int tid = threadIdx.x, wid = tid >> 6, lane = tid & 63;
  xs[tid] = x[(size_t)p * KD + tid];
  __syncthreads();
  const float4 xv = ((const float4*)xs)[lane];
  float bestS = 3.4e38f; int bestI = 0;
  for (int k = wid; k < N_CB; k += 4) {
    const float4 cv = ((const float4*)cb)[(size_t)k * 64 + lane];
    float t = cv.x*(cv.x - 2.f*xv.x) + cv.y*(cv.y - 2.f*xv.y)
            + cv.z*(cv.z - 2.f*xv.z) + cv.w*(cv.w - 2.f*xv.w);
    #pragma unroll
    for (int off = 1; off < 64; off <<= 1) t += __shfl_xor(t, off);
    if (t < bestS) { bestS = t; bestI = k; }
  }
  if (lane == 0)
    keys[wid] = ((unsigned long long)fkey(bestS) << 32) | (unsigned int)bestI;
  __syncthreads();
  if (tid == 0) {
    unsigned long long m = keys[0];
    for (int i = 1; i < 4; i++) if (keys[i] < m) m = keys[i];
    widx = (int)(unsigned int)(m & 0xFFFFFFFFULL);
  }
  __syncthreads();
  out[(size_t)p * KD + tid] = cb[(size_t)widx * KD + tid];
}

extern "C" void kernel_launch(void* const* d_in, const int* in_sizes, int n_in,
                              void* d_out, int out_size, void* d_ws, size_t ws_size,
                              hipStream_t stream) {
  const float* x  = (const float*)d_in[0];   // [8192,256]
  const float* cb = (const float*)d_in[1];   // [16384,256]
  float* out = (float*)d_out;                // [8192,256]

  if (ws_size < WS_REQ) {   // ws_size is fixed per session -> graph-consistent
    fallback_kernel<<<M_PIX, 256, 0, stream>>>(x, cb, out);
    return;
  }

  char* ws = (char*)d_ws;
  unsigned short* Ch = (unsigned short*)(ws + OFF_CH);
  unsigned short* Cl = (unsigned short*)(ws + OFF_CL);
  unsigned short* Xh = (unsigned short*)(ws + OFF_XH);
  unsigned short* Xl = (unsigned short*)(ws + OFF_XL);
  float* cbsq        = (float*)(ws + OFF_CBSQ);
  ulonglong2* slots  = (ulonglong2*)(ws + OFF_SLOT);

  prep_kernel<<<(N_CB + M_PIX) / 4, 256, 0, stream>>>(x, cb, Ch, Cl, Xh, Xl, cbsq);
  gemm_top2_kernel<<<dim3(N_CB / 128, M_PIX / 128), 256, 0, stream>>>(Xh, Xl, Ch, Cl, cbsq, slots);
  reduce_gather_kernel<<<M_PIX / 4, 256, 0, stream>>>(x, cb, cbsq, slots, out);
}

// Round 2
// 391.306 us; speedup vs baseline: 1.3707x; 1.3707x over previous
//
#include <hip/hip_runtime.h>
#include <stdint.h>

#define M_PIX 8192
#define N_CB  16384
#define KD    256

typedef float  f32x4  __attribute__((ext_vector_type(4)));
typedef __bf16 bf16x8 __attribute__((ext_vector_type(8)));

// workspace layout (bytes)
#define OFF_CH   (0ULL)            // codebook hi  : 16384*256*2 = 8 MB
#define OFF_CL   (8ULL  << 20)     // codebook lo  : 8 MB
#define OFF_XH   (16ULL << 20)     // x hi         : 4 MB
#define OFF_XL   (20ULL << 20)     // x lo         : 4 MB
#define OFF_CBSQ (24ULL << 20)     // ||c||^2 fp32 : 64 KB
#define OFF_SLOT (25ULL << 20)     // top2 slots   : 8192*128*16 = 16 MB
#define WS_REQ   ((25ULL << 20) + (16ULL << 20))

__device__ __forceinline__ unsigned short f2bf(float v) {
  unsigned int u = __float_as_uint(v);
  u += 0x7FFFu + ((u >> 16) & 1u);   // round-to-nearest-even to bf16
  return (unsigned short)(u >> 16);
}
__device__ __forceinline__ float bf2f(unsigned short h) {
  return __uint_as_float(((unsigned int)h) << 16);
}
// order-preserving map fp32 -> u32 (handles negatives)
__device__ __forceinline__ unsigned int fkey(float s) {
  unsigned int f = __float_as_uint(s);
  return f ^ ((unsigned int)(((int)f) >> 31) | 0x80000000u);
}

// async global->LDS, 16B per lane; lds dest = wave-uniform base + lane*16
__device__ __forceinline__ void gl_lds16(const unsigned short* g, unsigned short* l) {
  __builtin_amdgcn_global_load_lds(
      (const __attribute__((address_space(1))) unsigned int*)(const void*)g,
      (__attribute__((address_space(3))) unsigned int*)(void*)l,
      16, 0, 0);
}

// ---------------- kernel 1: convert to bf16 hi/lo + codebook norms ----------
__global__ __launch_bounds__(256) void prep_kernel(
    const float* __restrict__ x, const float* __restrict__ cb,
    unsigned short* __restrict__ Ch, unsigned short* __restrict__ Cl,
    unsigned short* __restrict__ Xh, unsigned short* __restrict__ Xl,
    float* __restrict__ cbsq) {
  const int wid = threadIdx.x >> 6, lane = threadIdx.x & 63;
  const int row = blockIdx.x * 4 + wid;        // grid = (N_CB+M_PIX)/4
  const bool isCb = (row < N_CB);
  const int rowL = isCb ? row : row - N_CB;
  const float* src = (isCb ? cb : x) + (size_t)rowL * KD;
  const float4 v = ((const float4*)src)[lane]; // 64 lanes * 4 = 256 elems

  unsigned short h0 = f2bf(v.x), h1 = f2bf(v.y), h2 = f2bf(v.z), h3 = f2bf(v.w);
  unsigned short l0 = f2bf(v.x - bf2f(h0)), l1 = f2bf(v.y - bf2f(h1)),
                 l2 = f2bf(v.z - bf2f(h2)), l3 = f2bf(v.w - bf2f(h3));
  uint2 ph = make_uint2((unsigned)h0 | ((unsigned)h1 << 16),
                        (unsigned)h2 | ((unsigned)h3 << 16));
  uint2 pl = make_uint2((unsigned)l0 | ((unsigned)l1 << 16),
                        (unsigned)l2 | ((unsigned)l3 << 16));
  const size_t o = (size_t)rowL * KD + (size_t)lane * 4;
  *(uint2*)(void*)((isCb ? Ch : Xh) + o) = ph;
  *(uint2*)(void*)((isCb ? Cl : Xl) + o) = pl;

  if (isCb) {
    float ss = v.x*v.x + v.y*v.y + v.z*v.z + v.w*v.w;  // fp32 norm (matches ref scale)
    #pragma unroll
    for (int off = 32; off > 0; off >>= 1) ss += __shfl_xor(ss, off);
    if (lane == 0) cbsq[row] = ss;
  }
}

// ---------------- kernel 2: LDS-staged split-bf16 GEMM + top-2 --------------
// s[p,n] = cbsq[n] - 2*(xh.ch + xh.cl + xl.ch)   (xl.cl dropped, ~4e-4 error)
// 8192 blocks, 256 thr = 4 waves (2x2), block tile 128x128, BK=32, K=256.
// LDS tiles staged via global_load_lds(16B); granule XOR-swizzle (no padding
// allowed with global_load_lds) keeps ds_read_b128 aliasing at 2-way (free).

#define BK 32

// fragment read with matching swizzle: row-major [128][32] bf16, granule=8 elems
__device__ __forceinline__ bf16x8 ldsfrag(const unsigned short* t, int row, int q) {
  return *(const bf16x8*)(const void*)(t + row * BK + ((q ^ ((row >> 1) & 3)) << 3));
}

__global__ __launch_bounds__(256, 4) void gemm_top2_kernel(
    const unsigned short* __restrict__ Xh, const unsigned short* __restrict__ Xl,
    const unsigned short* __restrict__ Ch, const unsigned short* __restrict__ Cl,
    const float* __restrict__ cbsq, ulonglong2* __restrict__ slots) {
  __shared__ __align__(16) unsigned short Ah_s[128 * BK], Al_s[128 * BK],
                                          Bh_s[128 * BK], Bl_s[128 * BK];
  __shared__ ulonglong2 lds_top[128][2];

  const int tid = threadIdx.x;
  const int wid = tid >> 6, lane = tid & 63;
  const int wy = wid >> 1, wx = wid & 1;
  const int q = lane >> 4, c = lane & 15;

  // XCD-aware swizzle: XCD x sweeps all 64 m-tiles of n-band [x*16, x*16+16)
  const int bx = blockIdx.x & 7, bg = blockIdx.x >> 3;
  const int nt = bx * 16 + (bg >> 6);   // 0..127
  const int mt = bg & 63;               // 0..63
  const int m0 = mt * 128, n0 = nt * 128;

  const f32x4 zf = {0.f, 0.f, 0.f, 0.f};
  f32x4 acc[4][4];
  #pragma unroll
  for (int i = 0; i < 4; i++)
    #pragma unroll
    for (int j = 0; j < 4; j++) acc[i][j] = zf;

  // staging addressing (shared by all 4 tiles): slot s = j*256+tid covers
  // (row = s>>2, granule gc = s&3); source granule is swizzle^-1 (= swizzle)
  const int wbase = tid & 192;  // wave-uniform slot base within 256

  for (int ks = 0; ks < 8; ks++) {
    const int kcol = ks * BK;
    __syncthreads();   // previous iter's ds_reads done before overwrite
    #pragma unroll
    for (int j = 0; j < 2; j++) {
      const int s = j * 256 + tid;
      const int row = s >> 2, gc = s & 3;
      const int gsrc = (gc ^ ((row >> 1) & 3)) << 3;   // element offset in row
      const size_t arow_off = (size_t)(m0 + row) * KD + kcol + gsrc;
      const size_t brow_off = (size_t)(n0 + row) * KD + kcol + gsrc;
      unsigned short* lbase = (unsigned short*)0 + (size_t)(j * 256 + wbase) * 8;
      gl_lds16(Xh + arow_off, Ah_s + (size_t)(j * 256 + wbase) * 8);
      gl_lds16(Xl + arow_off, Al_s + (size_t)(j * 256 + wbase) * 8);
      gl_lds16(Ch + brow_off, Bh_s + (size_t)(j * 256 + wbase) * 8);
      gl_lds16(Cl + brow_off, Bl_s + (size_t)(j * 256 + wbase) * 8);
      (void)lbase;
    }
    __syncthreads();   // compiler drains vmcnt(0) before barrier (m97 pattern)

    bf16x8 bh[4], bl[4];
    #pragma unroll
    for (int ni = 0; ni < 4; ni++) {
      const int brow = wx * 64 + ni * 16 + c;
      bh[ni] = ldsfrag(Bh_s, brow, q);
      bl[ni] = ldsfrag(Bl_s, brow, q);
    }
    #pragma unroll
    for (int mi = 0; mi < 4; mi++) {
      const int arow = wy * 64 + mi * 16 + c;
      const bf16x8 ah = ldsfrag(Ah_s, arow, q);
      const bf16x8 al = ldsfrag(Al_s, arow, q);
      #pragma unroll
      for (int ni = 0; ni < 4; ni++) {
        acc[mi][ni] = __builtin_amdgcn_mfma_f32_16x16x32_bf16(ah, bh[ni], acc[mi][ni], 0, 0, 0);
        acc[mi][ni] = __builtin_amdgcn_mfma_f32_16x16x32_bf16(ah, bl[ni], acc[mi][ni], 0, 0, 0);
        acc[mi][ni] = __builtin_amdgcn_mfma_f32_16x16x32_bf16(al, bh[ni], acc[mi][ni], 0, 0, 0);
      }
    }
  }

  // epilogue: C/D layout col=lane&15, row=quad*4+reg (verified m89/m91)
  float cs[4];
  #pragma unroll
  for (int ni = 0; ni < 4; ni++) cs[ni] = cbsq[n0 + wx * 64 + ni * 16 + c];

  #pragma unroll
  for (int mi = 0; mi < 4; mi++) {
    #pragma unroll
    for (int r = 0; r < 4; r++) {
      unsigned long long b1 = ~0ULL, b2 = ~0ULL;
      #pragma unroll
      for (int ni = 0; ni < 4; ni++) {
        const int n = n0 + wx * 64 + ni * 16 + c;
        const float s = fmaf(-2.f, acc[mi][ni][r], cs[ni]);
        const unsigned long long key =
            ((unsigned long long)fkey(s) << 32) | (unsigned int)n;
        unsigned long long lo = key < b1 ? key : b1;
        unsigned long long hi = key < b1 ? b1 : key;
        b1 = lo; b2 = hi < b2 ? hi : b2;
      }
      // top-2 across the 16 c-lanes (xor on lane bits 0-3 stays in group)
      #pragma unroll
      for (int off = 1; off < 16; off <<= 1) {
        unsigned long long o1 = __shfl_xor(b1, off), o2 = __shfl_xor(b2, off);
        unsigned long long m1 = b1 < o1 ? b1 : o1;
        unsigned long long t  = b1 < o1 ? o1 : b1;
        unsigned long long mo = b2 < o2 ? b2 : o2;
        b1 = m1; b2 = t < mo ? t : mo;
      }
      if (c == 0) lds_top[wy * 64 + mi * 16 + q * 4 + r][wx] = make_ulonglong2(b1, b2);
    }
  }
  __syncthreads();

  if (tid < 128) {
    const ulonglong2 a = lds_top[tid][0], b = lds_top[tid][1];
    unsigned long long m1 = a.x < b.x ? a.x : b.x;
    unsigned long long t  = a.x < b.x ? b.x : a.x;
    unsigned long long mo = a.y < b.y ? a.y : b.y;
    unsigned long long m2 = t < mo ? t : mo;
    slots[(size_t)(m0 + tid) * 128 + nt] = make_ulonglong2(m1, m2);
  }
}

// ---------------- kernel 3: global top-2, exact fp32 rescore, gather --------
__global__ __launch_bounds__(256) void reduce_gather_kernel(
    const float* __restrict__ x, const float* __restrict__ cb,
    const float* __restrict__ cbsq, const ulonglong2* __restrict__ slots,
    float* __restrict__ out) {
  const int wid = threadIdx.x >> 6, lane = threadIdx.x & 63;
  const int pixel = blockIdx.x * 4 + wid;     // grid = 8192/4
  const ulonglong2* sp = slots + (size_t)pixel * 128;
  const ulonglong2 s0 = sp[lane];
  const ulonglong2 s1 = sp[64 + lane];

  unsigned long long b1 = s0.x, b2 = s0.y;
  { unsigned long long m1 = b1 < s1.x ? b1 : s1.x;
    unsigned long long t  = b1 < s1.x ? s1.x : b1;
    unsigned long long mo = b2 < s1.y ? b2 : s1.y;
    b1 = m1; b2 = t < mo ? t : mo; }
  #pragma unroll
  for (int off = 1; off < 64; off <<= 1) {
    unsigned long long o1 = __shfl_xor(b1, off), o2 = __shfl_xor(b2, off);
    unsigned long long m1 = b1 < o1 ? b1 : o1;
    unsigned long long t  = b1 < o1 ? o1 : b1;
    unsigned long long mo = b2 < o2 ? b2 : o2;
    b1 = m1; b2 = t < mo ? t : mo;
  }
  const int i1 = (int)(unsigned int)(b1 & 0xFFFFFFFFULL);
  const int i2 = (int)(unsigned int)(b2 & 0xFFFFFFFFULL);

  const float4 xv = ((const float4*)x)[(size_t)pixel * 64 + lane];
  const float4 c1 = ((const float4*)cb)[(size_t)i1 * 64 + lane];
  const float4 c2 = ((const float4*)cb)[(size_t)i2 * 64 + lane];
  float d1 = xv.x*c1.x + xv.y*c1.y + xv.z*c1.z + xv.w*c1.w;
  float d2 = xv.x*c2.x + xv.y*c2.y + xv.z*c2.z + xv.w*c2.w;
  #pragma unroll
  for (int off = 1; off < 64; off <<= 1) {
    d1 += __shfl_xor(d1, off);
    d2 += __shfl_xor(d2, off);
  }
  const float s1v = fmaf(-2.f, d1, cbsq[i1]);
  const float s2v = fmaf(-2.f, d2, cbsq[i2]);
  const int w = (s1v < s2v) ? i1 : (s2v < s1v) ? i2 : (i1 < i2 ? i1 : i2);
  ((float4*)out)[(size_t)pixel * 64 + lane] = ((const float4*)cb)[(size_t)w * 64 + lane];
}

// ---------------- fallback (only if ws too small): exact fp32 scan ----------
__global__ __launch_bounds__(256) void fallback_kernel(
    const float* __restrict__ x, const float* __restrict__ cb,
    float* __restrict__ out) {
  __shared__ float xs[256];
  __shared__ unsigned long long keys[4];
  __shared__ int widx;
  const int p = blockIdx.x;
  const int tid = threadIdx.x, wid = tid >> 6, lane = tid & 63;
  xs[tid] = x[(size_t)p * KD + tid];
  __syncthreads();
  const float4 xv = ((const float4*)xs)[lane];
  float bestS = 3.4e38f; int bestI = 0;
  for (int k = wid; k < N_CB; k += 4) {
    const float4 cv = ((const float4*)cb)[(size_t)k * 64 + lane];
    float t = cv.x*(cv.x - 2.f*xv.x) + cv.y*(cv.y - 2.f*xv.y)
            + cv.z*(cv.z - 2.f*xv.z) + cv.w*(cv.w - 2.f*xv.w);
    #pragma unroll
    for (int off = 1; off < 64; off <<= 1) t += __shfl_xor(t, off);
    if (t < bestS) { bestS = t; bestI = k; }
  }
  if (lane == 0)
    keys[wid] = ((unsigned long long)fkey(bestS) << 32) | (unsigned int)bestI;
  __syncthreads();
  if (tid == 0) {
    unsigned long long m = keys[0];
    for (int i = 1; i < 4; i++) if (keys[i] < m) m = keys[i];
    widx = (int)(unsigned int)(m & 0xFFFFFFFFULL);
  }
  __syncthreads();
  out[(size_t)p * KD + tid] = cb[(size_t)widx * KD + tid];
}

extern "C" void kernel_launch(void* const* d_in, const int* in_sizes, int n_in,
                              void* d_out, int out_size, void* d_ws, size_t ws_size,
                              hipStream_t stream) {
  const float* x  = (const float*)d_in[0];   // [8192,256]
  const float* cb = (const float*)d_in[1];   // [16384,256]
  float* out = (float*)d_out;                // [8192,256]

  if (ws_size < WS_REQ) {   // ws_size is fixed per session -> graph-consistent
    fallback_kernel<<<M_PIX, 256, 0, stream>>>(x, cb, out);
    return;
  }

  char* ws = (char*)d_ws;
  unsigned short* Ch = (unsigned short*)(ws + OFF_CH);
  unsigned short* Cl = (unsigned short*)(ws + OFF_CL);
  unsigned short* Xh = (unsigned short*)(ws + OFF_XH);
  unsigned short* Xl = (unsigned short*)(ws + OFF_XL);
  float* cbsq        = (float*)(ws + OFF_CBSQ);
  ulonglong2* slots  = (ulonglong2*)(ws + OFF_SLOT);

  prep_kernel<<<(N_CB + M_PIX) / 4, 256, 0, stream>>>(x, cb, Ch, Cl, Xh, Xl, cbsq);
  gemm_top2_kernel<<<M_PIX, 256, 0, stream>>>(Xh, Xl, Ch, Cl, cbsq, slots);
  reduce_gather_kernel<<<M_PIX / 4, 256, 0, stream>>>(x, cb, cbsq, slots, out);
}

// Round 3
// 250.695 us; speedup vs baseline: 2.1395x; 1.5609x over previous
//
#include <hip/hip_runtime.h>
#include <stdint.h>

#define M_PIX 8192
#define N_CB  16384
#define KD    256
#define BK    64

typedef float  f32x4  __attribute__((ext_vector_type(4)));
typedef __bf16 bf16x8 __attribute__((ext_vector_type(8)));

// workspace layout (bytes)
#define OFF_CH    (0ULL)            // codebook hi : 16384*256*2 = 8 MB
#define OFF_XH    (8ULL  << 20)     // x hi        : 4 MB
#define OFF_XL    (12ULL << 20)     // x lo        : 4 MB
#define OFF_CBSQ  (16ULL << 20)     // ||c||^2     : 64 KB
#define OFF_SLOTA (17ULL << 20)     // uint4 keys  : 128*8192*16 = 16 MB
#define OFF_SLOTB (33ULL << 20)     // u32 idx3    : 4 MB
#define WS_REQ    (37ULL << 20)

__device__ __forceinline__ unsigned short f2bf(float v) {
  unsigned int u = __float_as_uint(v);
  u += 0x7FFFu + ((u >> 16) & 1u);   // RNE to bf16
  return (unsigned short)(u >> 16);
}
__device__ __forceinline__ float bf2f(unsigned short h) {
  return __uint_as_float(((unsigned int)h) << 16);
}
// order-preserving map fp32 -> u32
__device__ __forceinline__ unsigned int fkey(float s) {
  unsigned int f = __float_as_uint(s);
  return f ^ ((unsigned int)(((int)f) >> 31) | 0x80000000u);
}
__device__ __forceinline__ void gl_lds16(const unsigned short* g, unsigned short* l) {
  __builtin_amdgcn_global_load_lds(
      (const __attribute__((address_space(1))) unsigned int*)(const void*)g,
      (__attribute__((address_space(3))) unsigned int*)(void*)l,
      16, 0, 0);
}
// branchless keep-smallest-3 (strict <, ties keep earlier => lower col first)
__device__ __forceinline__ void ins3(float s, unsigned int col,
    float& v1, float& v2, float& v3,
    unsigned int& c1, unsigned int& c2, unsigned int& c3) {
  const bool l1 = s < v1, l2 = s < v2, l3 = s < v3;
  v3 = l2 ? v2 : (l3 ? s : v3);  c3 = l2 ? c2 : (l3 ? col : c3);
  v2 = l1 ? v1 : (l2 ? s : v2);  c2 = l1 ? c1 : (l2 ? col : c2);
  v1 = l1 ? s : v1;              c1 = l1 ? col : c1;
}
typedef unsigned long long ull;
__device__ __forceinline__ void ins4(ull k, ull& s1, ull& s2, ull& s3, ull& s4) {
  const bool l1 = k < s1, l2 = k < s2, l3 = k < s3, l4 = k < s4;
  s4 = l3 ? s3 : (l4 ? k : s4);
  s3 = l2 ? s2 : (l3 ? k : s3);
  s2 = l1 ? s1 : (l2 ? k : s2);
  s1 = l1 ? k : s1;
}

// ---------------- kernel 1: x -> bf16 hi/lo, cb -> bf16 hi + norms ----------
__global__ __launch_bounds__(256) void prep_kernel(
    const float* __restrict__ x, const float* __restrict__ cb,
    unsigned short* __restrict__ Ch, unsigned short* __restrict__ Xh,
    unsigned short* __restrict__ Xl, float* __restrict__ cbsq) {
  const int wid = threadIdx.x >> 6, lane = threadIdx.x & 63;
  const int row = blockIdx.x * 4 + wid;        // grid = (N_CB+M_PIX)/4
  const bool isCb = (row < N_CB);
  const int rowL = isCb ? row : row - N_CB;
  const float* src = (isCb ? cb : x) + (size_t)rowL * KD;
  const float4 v = ((const float4*)src)[lane];

  unsigned short h0 = f2bf(v.x), h1 = f2bf(v.y), h2 = f2bf(v.z), h3 = f2bf(v.w);
  uint2 ph = make_uint2((unsigned)h0 | ((unsigned)h1 << 16),
                        (unsigned)h2 | ((unsigned)h3 << 16));
  const size_t o = (size_t)rowL * KD + (size_t)lane * 4;
  if (isCb) {
    *(uint2*)(void*)(Ch + o) = ph;
    float ss = v.x*v.x + v.y*v.y + v.z*v.z + v.w*v.w;
    #pragma unroll
    for (int off = 32; off > 0; off >>= 1) ss += __shfl_xor(ss, off);
    if (lane == 0) cbsq[rowL] = ss;
  } else {
    unsigned short l0 = f2bf(v.x - bf2f(h0)), l1 = f2bf(v.y - bf2f(h1)),
                   l2 = f2bf(v.z - bf2f(h2)), l3 = f2bf(v.w - bf2f(h3));
    uint2 pl = make_uint2((unsigned)l0 | ((unsigned)l1 << 16),
                          (unsigned)l2 | ((unsigned)l3 << 16));
    *(uint2*)(void*)(Xh + o) = ph;
    *(uint2*)(void*)(Xl + o) = pl;
  }
}

// ---------------- kernel 2: split-bf16 GEMM + per-tile exact top-3 ----------
// s[p,n] = cbsq[n] - 2*(xh+xl).ch ; noise = codebook bf16 rounding only.
// 8192 blocks / 256 thr (4 waves 2x2); tile 128x128, BK=64 (4 K-iters).
// LDS: 3 tiles x 16 KB staged via global_load_lds(16B) + XOR granule swizzle;
// epilogue overlays dead tile LDS with a 64x132 fp32 score buffer (two halves).

__device__ __forceinline__ bf16x8 ldsfrag64(const unsigned short* t, int row, int g) {
  return *(const bf16x8*)(const void*)(t + row * BK + ((g ^ (row & 7)) << 3));
}

__global__ __launch_bounds__(256, 3) void gemm_top3_kernel(
    const unsigned short* __restrict__ Xh, const unsigned short* __restrict__ Xl,
    const unsigned short* __restrict__ Ch, const float* __restrict__ cbsq,
    uint4* __restrict__ slotsA, unsigned int* __restrict__ slotsB) {
  __shared__ __align__(16) char smem[49152];
  unsigned short* Ah_s = (unsigned short*)smem;            // 16 KB [128][64]
  unsigned short* Al_s = (unsigned short*)(smem + 16384);
  unsigned short* Bh_s = (unsigned short*)(smem + 32768);
  float* scanbuf = (float*)smem;                           // 64*132*4 = 33792 B
  unsigned int* partial = (unsigned int*)(smem + 33792);   // [64][28] = 7168 B

  const int tid = threadIdx.x;
  const int wid = tid >> 6, lane = tid & 63;
  const int wy = wid >> 1, wx = wid & 1;
  const int q = lane >> 4, c = lane & 15;

  // m-outer / n-inner per XCD: 16-block sweeps share one A-tile + 512KB B-strip
  const int bx = blockIdx.x & 7, bg = blockIdx.x >> 3;
  const int mt = bg >> 4;               // 0..63
  const int nt = bx * 16 + (bg & 15);   // 0..127
  const int m0 = mt * 128, n0 = nt * 128;

  const f32x4 zf = {0.f, 0.f, 0.f, 0.f};
  f32x4 acc[4][4];
  #pragma unroll
  for (int i = 0; i < 4; i++)
    #pragma unroll
    for (int j = 0; j < 4; j++) acc[i][j] = zf;

  #pragma unroll
  for (int ks = 0; ks < 4; ks++) {           // K = 4 * 64
    const int kcol = ks * BK;
    __syncthreads();
    #pragma unroll
    for (int j = 0; j < 4; j++) {            // 1024 granules per array
      const int s = j * 256 + tid;
      const int row = s >> 3, g = s & 7;
      const int gsw = (g ^ (row & 7)) << 3;  // element offset of source granule
      const size_t aoff = (size_t)(m0 + row) * KD + kcol + gsw;
      const size_t boff = (size_t)(n0 + row) * KD + kcol + gsw;
      const int lb = (j * 256 + (tid & 192)) * 8;   // wave-uniform LDS base
      gl_lds16(Xh + aoff, Ah_s + lb);
      gl_lds16(Xl + aoff, Al_s + lb);
      gl_lds16(Ch + boff, Bh_s + lb);
    }
    __syncthreads();
    #pragma unroll
    for (int kh = 0; kh < 2; kh++) {
      const int g = kh * 4 + q;
      bf16x8 bh[4];
      #pragma unroll
      for (int ni = 0; ni < 4; ni++) bh[ni] = ldsfrag64(Bh_s, wx * 64 + ni * 16 + c, g);
      #pragma unroll
      for (int mi = 0; mi < 4; mi++) {
        const int ar = wy * 64 + mi * 16 + c;
        const bf16x8 ah = ldsfrag64(Ah_s, ar, g);
        const bf16x8 al = ldsfrag64(Al_s, ar, g);
        #pragma unroll
        for (int ni = 0; ni < 4; ni++) {
          acc[mi][ni] = __builtin_amdgcn_mfma_f32_16x16x32_bf16(ah, bh[ni], acc[mi][ni], 0, 0, 0);
          acc[mi][ni] = __builtin_amdgcn_mfma_f32_16x16x32_bf16(al, bh[ni], acc[mi][ni], 0, 0, 0);
        }
      }
    }
  }
  __syncthreads();   // tiles dead; safe to overlay scanbuf

  float cs[4];
  #pragma unroll
  for (int ni = 0; ni < 4; ni++) cs[ni] = cbsq[n0 + wx * 64 + ni * 16 + c];

  const float FINF = __uint_as_float(0x7F800000u);
  float hv[2][3]; unsigned int hc[2][3];

  #pragma unroll
  for (int half = 0; half < 2; half++) {
    if (wy == half) {   // wave-uniform branch; C/D layout col=lane&15,row=q*4+r
      #pragma unroll
      for (int mi = 0; mi < 4; mi++)
        #pragma unroll
        for (int r = 0; r < 4; r++) {
          const int lrow = mi * 16 + q * 4 + r;
          #pragma unroll
          for (int ni = 0; ni < 4; ni++)
            scanbuf[lrow * 132 + wx * 64 + ni * 16 + c] =
                fmaf(-2.f, acc[mi][ni][r], cs[ni]);
        }
    }
    __syncthreads();
    {   // 4 threads per row scan 32 cols each
      const int srow = tid >> 2, cb0 = (tid & 3) * 32;
      float v1 = FINF, v2 = FINF, v3 = FINF;
      unsigned int c1 = 0, c2 = 0, c3 = 0;
      #pragma unroll
      for (int g = 0; g < 8; g++) {
        const float4 sv = *(const float4*)(const void*)&scanbuf[srow * 132 + cb0 + g * 4];
        ins3(sv.x, cb0 + g * 4 + 0, v1, v2, v3, c1, c2, c3);
        ins3(sv.y, cb0 + g * 4 + 1, v1, v2, v3, c1, c2, c3);
        ins3(sv.z, cb0 + g * 4 + 2, v1, v2, v3, c1, c2, c3);
        ins3(sv.w, cb0 + g * 4 + 3, v1, v2, v3, c1, c2, c3);
      }
      unsigned int* pb = partial + srow * 28 + (tid & 3) * 6;
      pb[0] = __float_as_uint(v1); pb[1] = __float_as_uint(v2);
      pb[2] = __float_as_uint(v3); pb[3] = c1; pb[4] = c2; pb[5] = c3;
    }
    __syncthreads();
    if (tid < 64) {   // merge 4 partials -> row top-3
      float v1 = FINF, v2 = FINF, v3 = FINF;
      unsigned int c1 = 0, c2 = 0, c3 = 0;
      #pragma unroll
      for (int p = 0; p < 4; p++) {
        const unsigned int* pb = partial + tid * 28 + p * 6;
        #pragma unroll
        for (int j = 0; j < 3; j++)
          ins3(__uint_as_float(pb[j]), pb[3 + j], v1, v2, v3, c1, c2, c3);
      }
      hv[half][0] = v1; hv[half][1] = v2; hv[half][2] = v3;
      hc[half][0] = c1; hc[half][1] = c2; hc[half][2] = c3;
    }
    __syncthreads();
  }

  if (tid < 64) {   // coalesced transposed slot writes: [tile][pixel]
    #pragma unroll
    for (int half = 0; half < 2; half++) {
      const int pixel = m0 + half * 64 + tid;
      const unsigned int i1 = n0 + hc[half][0];
      const unsigned int i2 = n0 + hc[half][1];
      const unsigned int i3 = n0 + hc[half][2];
      const size_t si = (size_t)nt * M_PIX + pixel;
      slotsA[si] = make_uint4(fkey(hv[half][0]), fkey(hv[half][1]),
                              fkey(hv[half][2]), i1 | (i2 << 16));
      slotsB[si] = i3;
    }
  }
}

// ---------------- kernel 3: merge 128x3 -> top-4, exact rescore, gather -----
__global__ __launch_bounds__(256) void reduce_rescore_gather(
    const float* __restrict__ x, const float* __restrict__ cb,
    const float* __restrict__ cbsq, const uint4* __restrict__ slotsA,
    const unsigned int* __restrict__ slotsB, float* __restrict__ out) {
  const int wid = threadIdx.x >> 6, lane = threadIdx.x & 63;
  const int pixel = blockIdx.x * 4 + wid;     // grid = 8192/4

  ull s1 = ~0ULL, s2 = ~0ULL, s3 = ~0ULL, s4 = ~0ULL;
  #pragma unroll
  for (int t = 0; t < 2; t++) {
    const size_t si = (size_t)(t * 64 + lane) * M_PIX + pixel;
    const uint4 A = slotsA[si];
    const unsigned int i3 = slotsB[si];
    ins4(((ull)A.x << 32) | (A.w & 0xFFFFu), s1, s2, s3, s4);
    ins4(((ull)A.y << 32) | (A.w >> 16),     s1, s2, s3, s4);
    ins4(((ull)A.z << 32) | i3,              s1, s2, s3, s4);
  }
  #pragma unroll
  for (int off = 1; off < 64; off <<= 1) {
    const ull o1 = __shfl_xor(s1, off), o2 = __shfl_xor(s2, off),
              o3 = __shfl_xor(s3, off), o4 = __shfl_xor(s4, off);
    ins4(o1, s1, s2, s3, s4); ins4(o2, s1, s2, s3, s4);
    ins4(o3, s1, s2, s3, s4); ins4(o4, s1, s2, s3, s4);
  }
  // all lanes now hold the identical global top-4; rescore exactly in fp32
  const float4 xv = ((const float4*)x)[(size_t)pixel * 64 + lane];
  const ull ks[4] = {s1, s2, s3, s4};
  ull best = ~0ULL;
  #pragma unroll
  for (int j = 0; j < 4; j++) {
    const unsigned int ij = (unsigned int)(ks[j] & 0xFFFFFFFFULL);
    const float4 cv = ((const float4*)cb)[(size_t)ij * 64 + lane];
    float d = xv.x*cv.x + xv.y*cv.y + xv.z*cv.z + xv.w*cv.w;
    #pragma unroll
    for (int off = 1; off < 64; off <<= 1) d += __shfl_xor(d, off);
    const float sc = fmaf(-2.f, d, cbsq[ij]);
    const ull k = ((ull)fkey(sc) << 32) | ij;   // tie -> lowest index
    best = k < best ? k : best;
  }
  const unsigned int w = (unsigned int)(best & 0xFFFFFFFFULL);
  ((float4*)out)[(size_t)pixel * 64 + lane] = ((const float4*)cb)[(size_t)w * 64 + lane];
}

// ---------------- fallback (ws too small): exact fp32 scan ------------------
__global__ __launch_bounds__(256) void fallback_kernel(
    const float* __restrict__ x, const float* __restrict__ cb,
    float* __restrict__ out) {
  __shared__ float xs[256];
  __shared__ unsigned long long keys[4];
  __shared__ int widx;
  const int p = blockIdx.x;
  const int tid = threadIdx.x, wid = tid >> 6, lane = tid & 63;
  xs[tid] = x[(size_t)p * KD + tid];
  __syncthreads();
  const float4 xv = ((const float4*)xs)[lane];
  float bestS = 3.4e38f; int bestI = 0;
  for (int k = wid; k < N_CB; k += 4) {
    const float4 cv = ((const float4*)cb)[(size_t)k * 64 + lane];
    float t = cv.x*(cv.x - 2.f*xv.x) + cv.y*(cv.y - 2.f*xv.y)
            + cv.z*(cv.z - 2.f*xv.z) + cv.w*(cv.w - 2.f*xv.w);
    #pragma unroll
    for (int off = 1; off < 64; off <<= 1) t += __shfl_xor(t, off);
    if (t < bestS) { bestS = t; bestI = k; }
  }
  if (lane == 0)
    keys[wid] = ((unsigned long long)fkey(bestS) << 32) | (unsigned int)bestI;
  __syncthreads();
  if (tid == 0) {
    unsigned long long m = keys[0];
    for (int i = 1; i < 4; i++) if (keys[i] < m) m = keys[i];
    widx = (int)(unsigned int)(m & 0xFFFFFFFFULL);
  }
  __syncthreads();
  out[(size_t)p * KD + tid] = cb[(size_t)widx * KD + tid];
}

extern "C" void kernel_launch(void* const* d_in, const int* in_sizes, int n_in,
                              void* d_out, int out_size, void* d_ws, size_t ws_size,
                              hipStream_t stream) {
  const float* x  = (const float*)d_in[0];   // [8192,256]
  const float* cb = (const float*)d_in[1];   // [16384,256]
  float* out = (float*)d_out;                // [8192,256]

  if (ws_size < WS_REQ) {
    fallback_kernel<<<M_PIX, 256, 0, stream>>>(x, cb, out);
    return;
  }

  char* ws = (char*)d_ws;
  unsigned short* Ch = (unsigned short*)(ws + OFF_CH);
  unsigned short* Xh = (unsigned short*)(ws + OFF_XH);
  unsigned short* Xl = (unsigned short*)(ws + OFF_XL);
  float* cbsq        = (float*)(ws + OFF_CBSQ);
  uint4* slotsA      = (uint4*)(ws + OFF_SLOTA);
  unsigned int* slotsB = (unsigned int*)(ws + OFF_SLOTB);

  prep_kernel<<<(N_CB + M_PIX) / 4, 256, 0, stream>>>(x, cb, Ch, Xh, Xl, cbsq);
  gemm_top3_kernel<<<M_PIX, 256, 0, stream>>>(Xh, Xl, Ch, cbsq, slotsA, slotsB);
  reduce_rescore_gather<<<M_PIX / 4, 256, 0, stream>>>(x, cb, cbsq, slotsA, slotsB, out);
}

// Round 4
// 197.429 us; speedup vs baseline: 2.7167x; 1.2698x over previous
//
#include <hip/hip_runtime.h>
#include <stdint.h>

#define M_PIX 8192
#define N_CB  16384
#define KD    256
#define BK    64

typedef float  f32x4  __attribute__((ext_vector_type(4)));
typedef __bf16 bf16x8 __attribute__((ext_vector_type(8)));

// workspace layout (bytes)
#define OFF_CH    (0ULL)            // codebook bf16 : 16384*256*2 = 8 MB
#define OFF_XH    (8ULL  << 20)     // x bf16        : 4 MB
#define OFF_CBSQ  (12ULL << 20)     // ||c||^2 fp32  : 64 KB
#define OFF_SLOT  (13ULL << 20)     // uint4/tilepix : 128*8192*16 = 16 MB
#define WS_REQ    (29ULL << 20)

__device__ __forceinline__ unsigned short f2bf(float v) {
  unsigned int u = __float_as_uint(v);
  u += 0x7FFFu + ((u >> 16) & 1u);   // RNE to bf16
  return (unsigned short)(u >> 16);
}
// order-preserving map fp32 -> u32
__device__ __forceinline__ unsigned int fkey(float s) {
  unsigned int f = __float_as_uint(s);
  return f ^ ((unsigned int)(((int)f) >> 31) | 0x80000000u);
}
__device__ __forceinline__ void gl_lds16(const unsigned short* g, unsigned short* l) {
  __builtin_amdgcn_global_load_lds(
      (const __attribute__((address_space(1))) unsigned int*)(const void*)g,
      (__attribute__((address_space(3))) unsigned int*)(void*)l,
      16, 0, 0);
}
// branchless keep-smallest-2 (strict <: ties keep earlier => lower col; a tied
// later col lands in v2, so both tie candidates survive to the exact rescore)
__device__ __forceinline__ void ins2(float s, unsigned int col,
    float& v1, float& v2, unsigned int& c1, unsigned int& c2) {
  const bool l1 = s < v1, l2 = s < v2;
  v2 = l1 ? v1 : (l2 ? s : v2);  c2 = l1 ? c1 : (l2 ? col : c2);
  v1 = l1 ? s : v1;              c1 = l1 ? col : c1;
}
typedef unsigned long long ull;
__device__ __forceinline__ void ins4(ull k, ull& s1, ull& s2, ull& s3, ull& s4) {
  const bool l1 = k < s1, l2 = k < s2, l3 = k < s3, l4 = k < s4;
  s4 = l3 ? s3 : (l4 ? k : s4);
  s3 = l2 ? s2 : (l3 ? k : s3);
  s2 = l1 ? s1 : (l2 ? k : s2);
  s1 = l1 ? k : s1;
}

// ---------------- kernel 1: fp32 -> bf16 (RNE) + codebook norms -------------
__global__ __launch_bounds__(256) void prep_kernel(
    const float* __restrict__ x, const float* __restrict__ cb,
    unsigned short* __restrict__ Ch, unsigned short* __restrict__ Xh,
    float* __restrict__ cbsq) {
  const int wid = threadIdx.x >> 6, lane = threadIdx.x & 63;
  const int row = blockIdx.x * 4 + wid;        // grid = (N_CB+M_PIX)/4
  const bool isCb = (row < N_CB);
  const int rowL = isCb ? row : row - N_CB;
  const float* src = (isCb ? cb : x) + (size_t)rowL * KD;
  const float4 v = ((const float4*)src)[lane];

  unsigned short h0 = f2bf(v.x), h1 = f2bf(v.y), h2 = f2bf(v.z), h3 = f2bf(v.w);
  uint2 ph = make_uint2((unsigned)h0 | ((unsigned)h1 << 16),
                        (unsigned)h2 | ((unsigned)h3 << 16));
  const size_t o = (size_t)rowL * KD + (size_t)lane * 4;
  *(uint2*)(void*)((isCb ? Ch : Xh) + o) = ph;
  if (isCb) {
    float ss = v.x*v.x + v.y*v.y + v.z*v.z + v.w*v.w;   // fp32 norm
    #pragma unroll
    for (int off = 32; off > 0; off >>= 1) ss += __shfl_xor(ss, off);
    if (lane == 0) cbsq[rowL] = ss;
  }
}

// ---------------- kernel 2: bf16 GEMM + per-tile top-2 ----------------------
// s[p,n] = cbsq[n] - 2*(xh.ch); noise sigma ~0.05 vs near-min gap ~9.4 =>
// per-tile top-2 + global top-4 exact rescore is safe (~1e-9/pixel).
// 8192 blocks / 256 thr (4 waves 2x2); tile 128x128, BK=64 (4 K-iters).
// Tiles staged via global_load_lds(16B) + XOR granule swizzle. Epilogue:
// scores -> 32-row scanbuf (4 phases), 8 thr/row ins2 scan, shuffle merge.

__device__ __forceinline__ bf16x8 ldsfrag64(const unsigned short* t, int row, int g) {
  return *(const bf16x8*)(const void*)(t + row * BK + ((g ^ (row & 7)) << 3));
}

__global__ __launch_bounds__(256, 3) void gemm_top2_kernel(
    const unsigned short* __restrict__ Xh, const unsigned short* __restrict__ Ch,
    const float* __restrict__ cbsq, uint4* __restrict__ slots) {
  __shared__ __align__(16) unsigned short Ah_s[128 * BK];   // 16 KB
  __shared__ __align__(16) unsigned short Bh_s[128 * BK];   // 16 KB
  __shared__ __align__(16) float scanbuf[32 * 132];         // 16.5 KB

  const int tid = threadIdx.x;
  const int wid = tid >> 6, lane = tid & 63;
  const int wy = wid >> 1, wx = wid & 1;
  const int q = lane >> 4, c = lane & 15;

  // m-outer / n-inner per XCD: 16-block sweeps share one A-tile + 512KB B-strip
  const int bx = blockIdx.x & 7, bg = blockIdx.x >> 3;
  const int mt = bg >> 4;               // 0..63
  const int nt = bx * 16 + (bg & 15);   // 0..127
  const int m0 = mt * 128, n0 = nt * 128;

  const f32x4 zf = {0.f, 0.f, 0.f, 0.f};
  f32x4 acc[4][4];
  #pragma unroll
  for (int i = 0; i < 4; i++)
    #pragma unroll
    for (int j = 0; j < 4; j++) acc[i][j] = zf;

  #pragma unroll
  for (int ks = 0; ks < 4; ks++) {           // K = 4 * 64
    const int kcol = ks * BK;
    __syncthreads();
    #pragma unroll
    for (int j = 0; j < 4; j++) {            // 1024 granules per array
      const int s = j * 256 + tid;
      const int row = s >> 3, g = s & 7;
      const int gsw = (g ^ (row & 7)) << 3;  // source granule (swizzle = inverse)
      const size_t aoff = (size_t)(m0 + row) * KD + kcol + gsw;
      const size_t boff = (size_t)(n0 + row) * KD + kcol + gsw;
      const int lb = (j * 256 + (tid & 192)) * 8;   // wave-uniform LDS base
      gl_lds16(Xh + aoff, Ah_s + lb);
      gl_lds16(Ch + boff, Bh_s + lb);
    }
    __syncthreads();
    #pragma unroll
    for (int kh = 0; kh < 2; kh++) {
      const int g = kh * 4 + q;
      bf16x8 bh[4];
      #pragma unroll
      for (int ni = 0; ni < 4; ni++) bh[ni] = ldsfrag64(Bh_s, wx * 64 + ni * 16 + c, g);
      #pragma unroll
      for (int mi = 0; mi < 4; mi++) {
        const bf16x8 ah = ldsfrag64(Ah_s, wy * 64 + mi * 16 + c, g);
        #pragma unroll
        for (int ni = 0; ni < 4; ni++)
          acc[mi][ni] = __builtin_amdgcn_mfma_f32_16x16x32_bf16(ah, bh[ni], acc[mi][ni], 0, 0, 0);
      }
    }
  }

  float cs[4];
  #pragma unroll
  for (int ni = 0; ni < 4; ni++) cs[ni] = cbsq[n0 + wx * 64 + ni * 16 + c];

  const float FINF = __uint_as_float(0x7F800000u);

  // 4 phases of 32 block-rows; phase p owned by waves wy == p>>1, mi in
  // {2*(p&1), 2*(p&1)+1}. C/D layout: col=lane&15, row=q*4+reg (m89/m91).
  #pragma unroll
  for (int p = 0; p < 4; p++) {
    if (p) __syncthreads();               // scanbuf reads of phase p-1 done
    if (wy == (p >> 1)) {
      #pragma unroll
      for (int mm = 0; mm < 2; mm++) {
        const int mi = (p & 1) * 2 + mm;
        #pragma unroll
        for (int r = 0; r < 4; r++) {
          const int lrow = mm * 16 + q * 4 + r;
          #pragma unroll
          for (int ni = 0; ni < 4; ni++)
            scanbuf[lrow * 132 + wx * 64 + ni * 16 + c] =
                fmaf(-2.f, acc[mi][ni][r], cs[ni]);
        }
      }
    }
    __syncthreads();
    // scan: 8 threads per row, 16 cols each
    const int srow = tid >> 3, seg = tid & 7;
    float v1 = FINF, v2 = FINF;
    unsigned int c1 = 0, c2 = 0;
    const float* rb = &scanbuf[srow * 132 + seg * 16];
    #pragma unroll
    for (int jj = 0; jj < 4; jj++) {
      const float4 sv = *(const float4*)(const void*)(rb + jj * 4);
      const unsigned int cb0 = seg * 16 + jj * 4;
      ins2(sv.x, cb0 + 0, v1, v2, c1, c2);
      ins2(sv.y, cb0 + 1, v1, v2, c1, c2);
      ins2(sv.z, cb0 + 2, v1, v2, c1, c2);
      ins2(sv.w, cb0 + 3, v1, v2, c1, c2);
    }
    // merge across the 8 segment-lanes (adjacent lanes, same row)
    #pragma unroll
    for (int off = 1; off < 8; off <<= 1) {
      const float ov1 = __shfl_xor(v1, off), ov2 = __shfl_xor(v2, off);
      const unsigned int oc1 = __shfl_xor(c1, off), oc2 = __shfl_xor(c2, off);
      const bool l = ov1 < v1;
      const float nv1 = l ? ov1 : v1;  const unsigned int nc1 = l ? oc1 : c1;
      const float sec = l ? v1 : ov1;  const unsigned int sc  = l ? c1 : oc1;
      const bool m = ov2 < v2;
      const float mv = m ? ov2 : v2;   const unsigned int mc  = m ? oc2 : c2;
      const bool t = mv < sec;
      v1 = nv1; c1 = nc1;
      v2 = t ? mv : sec; c2 = t ? mc : sc;
    }
    if (seg == 0) {   // 32 lanes store 512B contiguous per phase
      slots[(size_t)nt * M_PIX + m0 + p * 32 + srow] =
          make_uint4(fkey(v1), fkey(v2), n0 + c1, n0 + c2);
    }
  }
}

// ---------------- kernel 3: merge 128x2 -> top-4, exact rescore, gather -----
__global__ __launch_bounds__(256) void reduce_rescore_gather(
    const float* __restrict__ x, const float* __restrict__ cb,
    const float* __restrict__ cbsq, const uint4* __restrict__ slots,
    float* __restrict__ out) {
  const int wid = threadIdx.x >> 6, lane = threadIdx.x & 63;
  const int pixel = blockIdx.x * 4 + wid;     // grid = 8192/4

  ull s1 = ~0ULL, s2 = ~0ULL, s3 = ~0ULL, s4 = ~0ULL;
  #pragma unroll
  for (int t = 0; t < 2; t++) {
    const size_t si = (size_t)(t * 64 + lane) * M_PIX + pixel;
    const uint4 A = slots[si];
    ins4(((ull)A.x << 32) | A.z, s1, s2, s3, s4);
    ins4(((ull)A.y << 32) | A.w, s1, s2, s3, s4);
  }
  #pragma unroll
  for (int off = 1; off < 64; off <<= 1) {
    const ull o1 = __shfl_xor(s1, off), o2 = __shfl_xor(s2, off),
              o3 = __shfl_xor(s3, off), o4 = __shfl_xor(s4, off);
    ins4(o1, s1, s2, s3, s4); ins4(o2, s1, s2, s3, s4);
    ins4(o3, s1, s2, s3, s4); ins4(o4, s1, s2, s3, s4);
  }
  // all lanes hold the identical global top-4; rescore exactly in fp32
  const float4 xv = ((const float4*)x)[(size_t)pixel * 64 + lane];
  const ull ks[4] = {s1, s2, s3, s4};
  ull best = ~0ULL;
  #pragma unroll
  for (int j = 0; j < 4; j++) {
    const unsigned int ij = (unsigned int)(ks[j] & 0xFFFFFFFFULL);
    const float4 cv = ((const float4*)cb)[(size_t)ij * 64 + lane];
    float d = xv.x*cv.x + xv.y*cv.y + xv.z*cv.z + xv.w*cv.w;
    #pragma unroll
    for (int off = 1; off < 64; off <<= 1) d += __shfl_xor(d, off);
    const float sc = fmaf(-2.f, d, cbsq[ij]);
    const ull k = ((ull)fkey(sc) << 32) | ij;   // tie -> lowest index (np argmin)
    best = k < best ? k : best;
  }
  const unsigned int w = (unsigned int)(best & 0xFFFFFFFFULL);
  ((float4*)out)[(size_t)pixel * 64 + lane] = ((const float4*)cb)[(size_t)w * 64 + lane];
}

// ---------------- fallback (ws too small): exact fp32 scan ------------------
__global__ __launch_bounds__(256) void fallback_kernel(
    const float* __restrict__ x, const float* __restrict__ cb,
    float* __restrict__ out) {
  __shared__ float xs[256];
  __shared__ unsigned long long keys[4];
  __shared__ int widx;
  const int p = blockIdx.x;
  const int tid = threadIdx.x, wid = tid >> 6, lane = tid & 63;
  xs[tid] = x[(size_t)p * KD + tid];
  __syncthreads();
  const float4 xv = ((const float4*)xs)[lane];
  float bestS = 3.4e38f; int bestI = 0;
  for (int k = wid; k < N_CB; k += 4) {
    const float4 cv = ((const float4*)cb)[(size_t)k * 64 + lane];
    float t = cv.x*(cv.x - 2.f*xv.x) + cv.y*(cv.y - 2.f*xv.y)
            + cv.z*(cv.z - 2.f*xv.z) + cv.w*(cv.w - 2.f*xv.w);
    #pragma unroll
    for (int off = 1; off < 64; off <<= 1) t += __shfl_xor(t, off);
    if (t < bestS) { bestS = t; bestI = k; }
  }
  if (lane == 0)
    keys[wid] = ((unsigned long long)fkey(bestS) << 32) | (unsigned int)bestI;
  __syncthreads();
  if (tid == 0) {
    unsigned long long m = keys[0];
    for (int i = 1; i < 4; i++) if (keys[i] < m) m = keys[i];
    widx = (int)(unsigned int)(m & 0xFFFFFFFFULL);
  }
  __syncthreads();
  out[(size_t)p * KD + tid] = cb[(size_t)widx * KD + tid];
}

extern "C" void kernel_launch(void* const* d_in, const int* in_sizes, int n_in,
                              void* d_out, int out_size, void* d_ws, size_t ws_size,
                              hipStream_t stream) {
  const float* x  = (const float*)d_in[0];   // [8192,256]
  const float* cb = (const float*)d_in[1];   // [16384,256]
  float* out = (float*)d_out;                // [8192,256]

  if (ws_size < WS_REQ) {
    fallback_kernel<<<M_PIX, 256, 0, stream>>>(x, cb, out);
    return;
  }

  char* ws = (char*)d_ws;
  unsigned short* Ch = (unsigned short*)(ws + OFF_CH);
  unsigned short* Xh = (unsigned short*)(ws + OFF_XH);
  float* cbsq        = (float*)(ws + OFF_CBSQ);
  uint4* slots       = (uint4*)(ws + OFF_SLOT);

  prep_kernel<<<(N_CB + M_PIX) / 4, 256, 0, stream>>>(x, cb, Ch, Xh, cbsq);
  gemm_top2_kernel<<<M_PIX, 256, 0, stream>>>(Xh, Ch, cbsq, slots);
  reduce_rescore_gather<<<M_PIX / 4, 256, 0, stream>>>(x, cb, cbsq, slots, out);
}

// Round 5
// 174.561 us; speedup vs baseline: 3.0726x; 1.1310x over previous
//
#include <hip/hip_runtime.h>
#include <stdint.h>

#define M_PIX 8192
#define N_CB  16384
#define KD    256
#define BK    64

typedef float  f32x4  __attribute__((ext_vector_type(4)));
typedef __bf16 bf16x8 __attribute__((ext_vector_type(8)));
typedef unsigned long long ull;

// workspace layout (bytes)
#define OFF_CH    (0ULL)            // codebook bf16 : 16384*256*2 = 8 MB
#define OFF_XH    (8ULL  << 20)     // x bf16        : 4 MB
#define OFF_CBSQ  (12ULL << 20)     // ||c||^2 fp32  : 64 KB
#define OFF_SLOT  (13ULL << 20)     // ulonglong2    : 128*8192*16 = 16 MB
#define WS_REQ    (29ULL << 20)

__device__ __forceinline__ unsigned short f2bf(float v) {
  unsigned int u = __float_as_uint(v);
  u += 0x7FFFu + ((u >> 16) & 1u);   // RNE to bf16
  return (unsigned short)(u >> 16);
}
// order-preserving fp32 -> u32
__device__ __forceinline__ unsigned int fkey_u(unsigned int f) {
  return f ^ ((unsigned int)(((int)f) >> 31) | 0x80000000u);
}
__device__ __forceinline__ unsigned int fkey(float s) {
  return fkey_u(__float_as_uint(s));
}
__device__ __forceinline__ void gl_lds16(const unsigned short* g, unsigned short* l) {
  __builtin_amdgcn_global_load_lds(
      (const __attribute__((address_space(1))) unsigned int*)(const void*)g,
      (__attribute__((address_space(3))) unsigned int*)(void*)l,
      16, 0, 0);
}
// branchless keep-smallest-2 on packed float keys: 3 VALU insts, no cndmask
__device__ __forceinline__ void ins2f(float k, float& v1, float& v2) {
  v2 = fminf(v2, fmaxf(v1, k));   // uses OLD v1
  v1 = fminf(v1, k);
}

// ---------------- kernel 1: fp32 -> bf16 (RNE) + codebook norms -------------
__global__ __launch_bounds__(256) void prep_kernel(
    const float* __restrict__ x, const float* __restrict__ cb,
    unsigned short* __restrict__ Ch, unsigned short* __restrict__ Xh,
    float* __restrict__ cbsq) {
  const int wid = threadIdx.x >> 6, lane = threadIdx.x & 63;
  const int row = blockIdx.x * 4 + wid;        // grid = (N_CB+M_PIX)/4
  const bool isCb = (row < N_CB);
  const int rowL = isCb ? row : row - N_CB;
  const float* src = (isCb ? cb : x) + (size_t)rowL * KD;
  const float4 v = ((const float4*)src)[lane];

  unsigned short h0 = f2bf(v.x), h1 = f2bf(v.y), h2 = f2bf(v.z), h3 = f2bf(v.w);
  uint2 ph = make_uint2((unsigned)h0 | ((unsigned)h1 << 16),
                        (unsigned)h2 | ((unsigned)h3 << 16));
  const size_t o = (size_t)rowL * KD + (size_t)lane * 4;
  *(uint2*)(void*)((isCb ? Ch : Xh) + o) = ph;
  if (isCb) {
    float ss = v.x*v.x + v.y*v.y + v.z*v.z + v.w*v.w;   // fp32 norm
    #pragma unroll
    for (int off = 32; off > 0; off >>= 1) ss += __shfl_xor(ss, off);
    if (lane == 0) cbsq[rowL] = ss;
  }
}

// ---------------- kernel 2: bf16 GEMM + per-tile top-2 ----------------------
// s[p,n] = cbsq[n] - 2*(xh.ch); noise sigma ~0.05. Scores packed as fp32 with
// col in low 7 mantissa bits (error <=0.008, absorbed by kernel-3 rescore).
// 8192 blocks / 256 thr (4 waves 2x2); tile 128x128, BK=64 (4 K-iters).
// scanbuf overlays the dead A/B tile LDS after the K-loop -> 32.8 KB/block.

__device__ __forceinline__ bf16x8 ldsfrag64(const unsigned short* t, int row, int g) {
  return *(const bf16x8*)(const void*)(t + row * BK + ((g ^ (row & 7)) << 3));
}

__global__ __launch_bounds__(256, 4) void gemm_top2_kernel(
    const unsigned short* __restrict__ Xh, const unsigned short* __restrict__ Ch,
    const float* __restrict__ cbsq, ulonglong2* __restrict__ slots) {
  __shared__ __align__(16) char smem[32768];
  unsigned short* Ah_s = (unsigned short*)smem;          // 16 KB [128][64]
  unsigned short* Bh_s = (unsigned short*)(smem + 16384);
  float* scanbuf = (float*)smem;                         // overlay: 32*132*4 B

  const int tid = threadIdx.x;
  const int wid = tid >> 6, lane = tid & 63;
  const int wy = wid >> 1, wx = wid & 1;
  const int q = lane >> 4, c = lane & 15;

  // m-outer / n-inner per XCD: 16-block sweeps share one A-tile + 512KB B-strip
  const int bx = blockIdx.x & 7, bg = blockIdx.x >> 3;
  const int mt = bg >> 4;               // 0..63
  const int nt = bx * 16 + (bg & 15);   // 0..127
  const int m0 = mt * 128, n0 = nt * 128;

  const f32x4 zf = {0.f, 0.f, 0.f, 0.f};
  f32x4 acc[4][4];
  #pragma unroll
  for (int i = 0; i < 4; i++)
    #pragma unroll
    for (int j = 0; j < 4; j++) acc[i][j] = zf;

  #pragma unroll
  for (int ks = 0; ks < 4; ks++) {           // K = 4 * 64
    const int kcol = ks * BK;
    __syncthreads();
    #pragma unroll
    for (int j = 0; j < 4; j++) {            // 1024 granules per array
      const int s = j * 256 + tid;
      const int row = s >> 3, g = s & 7;
      const int gsw = (g ^ (row & 7)) << 3;  // source granule (swizzle = inverse)
      const size_t aoff = (size_t)(m0 + row) * KD + kcol + gsw;
      const size_t boff = (size_t)(n0 + row) * KD + kcol + gsw;
      const int lb = (j * 256 + (tid & 192)) * 8;   // wave-uniform LDS base
      gl_lds16(Xh + aoff, Ah_s + lb);
      gl_lds16(Ch + boff, Bh_s + lb);
    }
    __syncthreads();
    #pragma unroll
    for (int kh = 0; kh < 2; kh++) {
      const int g = kh * 4 + q;
      bf16x8 bh[4];
      #pragma unroll
      for (int ni = 0; ni < 4; ni++) bh[ni] = ldsfrag64(Bh_s, wx * 64 + ni * 16 + c, g);
      #pragma unroll
      for (int mi = 0; mi < 4; mi++) {
        const bf16x8 ah = ldsfrag64(Ah_s, wy * 64 + mi * 16 + c, g);
        #pragma unroll
        for (int ni = 0; ni < 4; ni++)
          acc[mi][ni] = __builtin_amdgcn_mfma_f32_16x16x32_bf16(ah, bh[ni], acc[mi][ni], 0, 0, 0);
      }
    }
  }

  float cs[4]; unsigned int colp[4];
  #pragma unroll
  for (int ni = 0; ni < 4; ni++) {
    cs[ni] = cbsq[n0 + wx * 64 + ni * 16 + c];
    colp[ni] = wx * 64 + ni * 16 + c;
  }
  const float FINF = __uint_as_float(0x7F800000u);

  // 4 phases of 32 block-rows; phase p owned by waves wy == p>>1, mi =
  // (p&1)*2+mm. C/D layout: col=lane&15, row=q*4+reg (m89/m91).
  #pragma unroll
  for (int p = 0; p < 4; p++) {
    __syncthreads();                      // prev reads done (also tile->overlay)
    if (wy == (p >> 1)) {
      #pragma unroll
      for (int mm = 0; mm < 2; mm++) {
        const int mi = (p & 1) * 2 + mm;
        #pragma unroll
        for (int r = 0; r < 4; r++) {
          const int lrow = mm * 16 + q * 4 + r;
          #pragma unroll
          for (int ni = 0; ni < 4; ni++) {
            const float s = fmaf(-2.f, acc[mi][ni][r], cs[ni]);
            scanbuf[lrow * 132 + colp[ni]] = __uint_as_float(
                (__float_as_uint(s) & 0xFFFFFF80u) | colp[ni]);
          }
        }
      }
    }
    __syncthreads();
    // scan: 8 threads per row, 16 cols each; packed keys -> min/max only
    const int srow = tid >> 3, seg = tid & 7;
    float v1 = FINF, v2 = FINF;
    const float* rb = &scanbuf[srow * 132 + seg * 16];
    #pragma unroll
    for (int jj = 0; jj < 4; jj++) {
      const float4 sv = *(const float4*)(const void*)(rb + jj * 4);
      ins2f(sv.x, v1, v2); ins2f(sv.y, v1, v2);
      ins2f(sv.z, v1, v2); ins2f(sv.w, v1, v2);
    }
    // merge across the 8 segment-lanes (lane bits 0-2)
    #pragma unroll
    for (int off = 1; off < 8; off <<= 1) {
      const float o1 = __shfl_xor(v1, off), o2 = __shfl_xor(v2, off);
      const float hi = fmaxf(v1, o1);
      v1 = fminf(v1, o1);
      v2 = fminf(fminf(v2, o2), hi);
    }
    if (seg == 0) {   // 8 lanes/wave, 128B contiguous stores
      const unsigned int u1 = __float_as_uint(v1), u2 = __float_as_uint(v2);
      slots[(size_t)nt * M_PIX + m0 + p * 32 + srow] = make_ulonglong2(
          ((ull)fkey_u(u1) << 32) | (unsigned int)(n0 + (u1 & 127u)),
          ((ull)fkey_u(u2) << 32) | (unsigned int)(n0 + (u2 & 127u)));
    }
  }
}

// ---------------- kernel 3: observed min + threshold exact rescore ----------
// Observed scores carry noise |eps| <~ 0.23 (4.5 sigma) + 0.008 packing.
// Candidates with observed < min+0.75 get exact fp32 rescore; excluded ones
// have true score >= min+0.75-0.23 > true(winner) <= min+0.23. Safe margin 2x.
__global__ __launch_bounds__(256) void reduce_rescore_gather(
    const float* __restrict__ x, const float* __restrict__ cb,
    const float* __restrict__ cbsq, const ulonglong2* __restrict__ slots,
    float* __restrict__ out) {
  const int wid = threadIdx.x >> 6, lane = threadIdx.x & 63;
  const int pixel = blockIdx.x * 4 + wid;     // grid = 8192/4

  const ulonglong2 sA = slots[(size_t)lane * M_PIX + pixel];
  const ulonglong2 sB = slots[(size_t)(64 + lane) * M_PIX + pixel];
  ull kk[4] = {sA.x, sA.y, sB.x, sB.y};
  ull mn = kk[0];
  mn = kk[1] < mn ? kk[1] : mn;
  mn = kk[2] < mn ? kk[2] : mn;
  mn = kk[3] < mn ? kk[3] : mn;
  #pragma unroll
  for (int off = 1; off < 64; off <<= 1) {
    const ull o = __shfl_xor(mn, off);
    mn = o < mn ? o : mn;
  }
  // threshold key = fkey(observed_min_score + 0.75)
  const unsigned int mu = (unsigned int)(mn >> 32);
  const unsigned int mb = mu ^ ((mu & 0x80000000u) ? 0x80000000u : 0xFFFFFFFFu);
  const float thrf = __uint_as_float(mb) + 0.75f;
  const unsigned int thr = fkey(thrf);

  ull bal[4]; int tot = 0;
  #pragma unroll
  for (int j = 0; j < 4; j++) {
    bal[j] = __ballot((unsigned int)(kk[j] >> 32) < thr);
    tot += __popcll(bal[j]);
  }

  const float4 xv = ((const float4*)x)[(size_t)pixel * 64 + lane];
  unsigned int w = (unsigned int)mn;
  if (tot > 1) {            // wave-uniform rare path (~8% of pixels)
    ull best = ~0ULL;
    #pragma unroll
    for (int j = 0; j < 4; j++) {
      ull mask = bal[j];
      while (mask) {
        const int src = (int)__ffsll((unsigned long long)mask) - 1;
        mask &= mask - 1;
        const ull key = __shfl(kk[j], src);
        const unsigned int ij = (unsigned int)key;
        const float4 cv = ((const float4*)cb)[(size_t)ij * 64 + lane];
        float d = xv.x*cv.x + xv.y*cv.y + xv.z*cv.z + xv.w*cv.w;
        #pragma unroll
        for (int off = 1; off < 64; off <<= 1) d += __shfl_xor(d, off);
        const float sc = fmaf(-2.f, d, cbsq[ij]);
        const ull ke = ((ull)fkey(sc) << 32) | ij;   // tie -> lowest idx
        best = ke < best ? ke : best;
      }
    }
    w = (unsigned int)best;
  }
  ((float4*)out)[(size_t)pixel * 64 + lane] = ((const float4*)cb)[(size_t)w * 64 + lane];
}

// ---------------- fallback (ws too small): exact fp32 scan ------------------
__global__ __launch_bounds__(256) void fallback_kernel(
    const float* __restrict__ x, const float* __restrict__ cb,
    float* __restrict__ out) {
  __shared__ float xs[256];
  __shared__ unsigned long long keys[4];
  __shared__ int widx;
  const int p = blockIdx.x;
  const int tid = threadIdx.x, wid = tid >> 6, lane = tid & 63;
  xs[tid] = x[(size_t)p * KD + tid];
  __syncthreads();
  const float4 xv = ((const float4*)xs)[lane];
  float bestS = 3.4e38f; int bestI = 0;
  for (int k = wid; k < N_CB; k += 4) {
    const float4 cv = ((const float4*)cb)[(size_t)k * 64 + lane];
    float t = cv.x*(cv.x - 2.f*xv.x) + cv.y*(cv.y - 2.f*xv.y)
            + cv.z*(cv.z - 2.f*xv.z) + cv.w*(cv.w - 2.f*xv.w);
    #pragma unroll
    for (int off = 1; off < 64; off <<= 1) t += __shfl_xor(t, off);
    if (t < bestS) { bestS = t; bestI = k; }
  }
  if (lane == 0)
    keys[wid] = ((unsigned long long)fkey(bestS) << 32) | (unsigned int)bestI;
  __syncthreads();
  if (tid == 0) {
    unsigned long long m = keys[0];
    for (int i = 1; i < 4; i++) if (keys[i] < m) m = keys[i];
    widx = (int)(unsigned int)(m & 0xFFFFFFFFULL);
  }
  __syncthreads();
  out[(size_t)p * KD + tid] = cb[(size_t)widx * KD + tid];
}

extern "C" void kernel_launch(void* const* d_in, const int* in_sizes, int n_in,
                              void* d_out, int out_size, void* d_ws, size_t ws_size,
                              hipStream_t stream) {
  const float* x  = (const float*)d_in[0];   // [8192,256]
  const float* cb = (const float*)d_in[1];   // [16384,256]
  float* out = (float*)d_out;                // [8192,256]

  if (ws_size < WS_REQ) {
    fallback_kernel<<<M_PIX, 256, 0, stream>>>(x, cb, out);
    return;
  }

  char* ws = (char*)d_ws;
  unsigned short* Ch = (unsigned short*)(ws + OFF_CH);
  unsigned short* Xh = (unsigned short*)(ws + OFF_XH);
  float* cbsq        = (float*)(ws + OFF_CBSQ);
  ulonglong2* slots  = (ulonglong2*)(ws + OFF_SLOT);

  prep_kernel<<<(N_CB + M_PIX) / 4, 256, 0, stream>>>(x, cb, Ch, Xh, cbsq);
  gemm_top2_kernel<<<M_PIX, 256, 0, stream>>>(Xh, Ch, cbsq, slots);
  reduce_rescore_gather<<<M_PIX / 4, 256, 0, stream>>>(x, cb, cbsq, slots, out);
}